// Round 1
// baseline (1027.008 us; speedup 1.0000x reference)
//
#include <hip/hip_runtime.h>
#include <hip/hip_bf16.h>

#define B_    16
#define CIN   64
#define COUT  64
#define ZD    64
#define WHID  32
#define TT    32768
#define KK    128
#define SS    256

typedef float f2 __attribute__((ext_vector_type(2)));
typedef float f4 __attribute__((ext_vector_type(4)));

// ---------------------------------------------------------------------------
// K0: tap-sum of wm2: wm2s[j][h] = sum_t wm2[(t*4096+j)*32+h], j<4096, h<32
// ---------------------------------------------------------------------------
__global__ void k_tapsum(const float* __restrict__ wm2, float* __restrict__ wm2s) {
    int i = blockIdx.x * 256 + threadIdx.x;
    if (i < 4096 * 32)
        wm2s[i] = wm2[i] + wm2[i + 131072] + wm2[i + 262144];
}

// ---------------------------------------------------------------------------
// K1: per-segment hypernet hidden h (stored) and bias (stored).
// ---------------------------------------------------------------------------
__global__ __launch_bounds__(256) void k_hyper_small(
    const float* __restrict__ z,
    const float* __restrict__ wm1, const float* __restrict__ wb1,
    const float* __restrict__ bm1, const float* __restrict__ bb1,
    const float* __restrict__ bm2, const float* __restrict__ bb2,
    float* __restrict__ ws_h, float* __restrict__ ws_bias)
{
    __shared__ float hb[8][32];
    const int tid = threadIdx.x;
    const int seg = tid >> 5, w = tid & 31;
    const int bk = blockIdx.x * 8 + seg;
    const int b = bk >> 7, k = bk & 127;
    const float* zp = z + b * ZD * KK + k;

    float hv = wb1[w], hbv = bb1[w];
    #pragma unroll
    for (int zz = 0; zz < 64; ++zz) {
        float zv = zp[zz * KK];
        hv  += wm1[w * 64 + zz] * zv;
        hbv += bm1[w * 64 + zz] * zv;
    }
    hv  = fmaxf(hv, 0.f);
    hbv = fmaxf(hbv, 0.f);
    ws_h[bk * 32 + w] = hv;
    hb[seg][w] = hbv;
    __syncthreads();

    #pragma unroll
    for (int t = 0; t < 2; ++t) {
        int o = w + t * 32;
        float acc = bb2[o];
        #pragma unroll
        for (int hh = 0; hh < 32; ++hh)
            acc += bm2[o * 32 + hh] * hb[seg][hh];
        ws_bias[bk * 64 + o] = acc;
    }
}

// ---------------------------------------------------------------------------
// K2: w_eff GEMM: ws_w[bk][j] = wm2s[j][:] @ h[bk][:] + tap-summed wb2[j]
// ---------------------------------------------------------------------------
__global__ __launch_bounds__(256) void k_weff(
    const float* __restrict__ wm2s, const float* __restrict__ wb2,
    const float* __restrict__ ws_h, float* __restrict__ ws_w)
{
    const int tid = threadIdx.x;
    const int wave = tid >> 6, lane = tid & 63;
    const int bk0 = blockIdx.x * 16 + wave * 4;

    float hreg[4][32];
    #pragma unroll
    for (int q = 0; q < 4; ++q) {
        #pragma unroll
        for (int hh = 0; hh < 32; ++hh)
            hreg[q][hh] = ws_h[(bk0 + q) * 32 + hh];
    }

    for (int jj = 0; jj < 64; ++jj) {
        int j = jj * 64 + lane;
        float4 row[8];
        const float4* rp = (const float4*)(wm2s + j * 32);
        #pragma unroll
        for (int q = 0; q < 8; ++q) row[q] = rp[q];
        float wb = wb2[j] + wb2[j + 4096] + wb2[j + 8192];
        const float* rowf = (const float*)row;
        #pragma unroll
        for (int q = 0; q < 4; ++q) {
            float acc = wb;
            #pragma unroll
            for (int hh = 0; hh < 32; ++hh)
                acc += rowf[hh] * hreg[q][hh];
            ws_w[(size_t)(bk0 + q) * 4096 + j] = acc;
        }
    }
}

// ---------------------------------------------------------------------------
// K3: fused main kernel. 1 block per (b,k) segment, 256 threads.
// Phase 1: y = sin(x_tile @ W + bias), y -> LDS (bf16).
//   x tile streamed through an LDS double-buffer (4 rows/chunk) aliased onto
//   the first 8KB of ybuf (dead until the pack step). Loads run 4 chunks
//   ahead of consumption. Inner products use packed fp32 (v_pk_fma_f32 via
//   float2 ext-vector arithmetic): weight pairs come free as .xy/.zw of the
//   b128 LDS broadcasts; x/y scalars are splatted.
// Phase 2: res = (rw@y + rb + x)/2, skip = sw@y + sb, packed fp32.
//   rw^T/sw^T staged via global gather (L2-hot 16KB) -> registers during the
//   sin/pack phase -> conflict-free coalesced LDS writes (kills the 64-way
//   bank conflict of the old transpose staging).
// LDS: U = 32KB union (W+bias | rwT+swT) + ybuf 32KB = exactly 64KB.
// ---------------------------------------------------------------------------
__global__ __launch_bounds__(256, 2) void k_main(
    const float* __restrict__ x,
    const float* __restrict__ ws_w, const float* __restrict__ ws_bias,
    const float* __restrict__ rw, const float* __restrict__ rb,
    const float* __restrict__ sw, const float* __restrict__ sb,
    float* __restrict__ out)
{
    __shared__ float U[8192];                               // 32 KB
    __shared__ __align__(16) unsigned short ybuf[64][256];  // 32 KB (bf16)

    const int tid = threadIdx.x;
    const int bk = blockIdx.x;
    const int b = bk >> 7, k = bk & 127;
    const int tbase = k * SS;
    const int sg = tid & 63, og = tid >> 6;
    const int s0 = sg * 4, o0 = og * 16;
    f4* U4 = (f4*)U;
    f4* xch = (f4*)&ybuf[0][0];   // [2 bufs][4 rows][64 f4] = 8 KB, aliases ybuf rows 0..15

    // ---- stage W (4096 floats) into U[0..4095]; bias into U[4096..4159] ----
    {
        const f4* Wg = (const f4*)(ws_w + (size_t)bk * 4096);
        #pragma unroll
        for (int r = 0; r < 4; ++r) U4[tid + 256 * r] = Wg[tid + 256 * r];
        if (tid < 64) U[4096 + tid] = ws_bias[bk * 64 + tid];
    }

    // ---- phase 1: y = sin(x @ W + bias), chunked x via LDS dbuf ----
    const float* xg = x + (size_t)b * CIN * TT + tbase + s0;   // + c*TT
    // prologue: L(0..3), W(0)
    f4 pend0 = *(const f4*)(xg + (size_t)(0  + og) * TT);
    f4 pend1 = *(const f4*)(xg + (size_t)(4  + og) * TT);
    f4 pend2 = *(const f4*)(xg + (size_t)(8  + og) * TT);
    f4 pend3 = *(const f4*)(xg + (size_t)(12 + og) * TT);
    xch[og * 64 + sg] = pend0;

    f2 acc[4][8];
    #pragma unroll
    for (int e = 0; e < 4; ++e)
        #pragma unroll
        for (int p = 0; p < 8; ++p) { f2 z = {0.f, 0.f}; acc[e][p] = z; }

    #pragma unroll 4
    for (int j = 0; j < 16; ++j) {
        __syncthreads();                       // xch[j&1] visible; prior reads of xch[(j+1)&1] done
        // L(j+4): issue next global load (consumed 3 iterations later)
        if (j + 4 < 16) {
            f4 v = *(const f4*)(xg + (size_t)((j + 4) * 4 + og) * TT);
            if      (((j + 4) & 3) == 0) pend0 = v;
            else if (((j + 4) & 3) == 1) pend1 = v;
            else if (((j + 4) & 3) == 2) pend2 = v;
            else                         pend3 = v;
        }
        // C(j): consume chunk j from xch[j&1]
        #pragma unroll
        for (int i = 0; i < 4; ++i) {
            f4 xv = xch[(j & 1) * 256 + i * 64 + sg];
            const int c = j * 4 + i;
            f2 xs0 = xv.xx, xs1 = xv.yy, xs2 = xv.zz, xs3 = xv.ww;
            #pragma unroll
            for (int q = 0; q < 4; ++q) {
                f4 wq = U4[c * 16 + og * 4 + q];
                f2 w0 = wq.xy, w1 = wq.zw;
                acc[0][2*q]   += xs0 * w0;  acc[0][2*q+1] += xs0 * w1;
                acc[1][2*q]   += xs1 * w0;  acc[1][2*q+1] += xs1 * w1;
                acc[2][2*q]   += xs2 * w0;  acc[2][2*q+1] += xs2 * w1;
                acc[3][2*q]   += xs3 * w0;  acc[3][2*q+1] += xs3 * w1;
            }
        }
        // W(j+1): stage chunk j+1 into the other buffer
        if (j + 1 < 16) {
            f4 w;
            if      (((j + 1) & 3) == 0) w = pend0;
            else if (((j + 1) & 3) == 1) w = pend1;
            else if (((j + 1) & 3) == 2) w = pend2;
            else                         w = pend3;
            xch[((j + 1) & 1) * 256 + og * 64 + sg] = w;
        }
    }
    __syncthreads();   // all chunk reads done: xch region may now be used as ybuf

    // prefetch rw/sw transpose gathers (L2-hot); latency hides under sin/pack
    float rgv[16], sgv[16];
    #pragma unroll
    for (int r = 0; r < 16; ++r) {
        int idx = r * 256 + tid;
        rgv[r] = rw[(idx & 63) * 64 + (idx >> 6)];
        sgv[r] = sw[(idx & 63) * 64 + (idx >> 6)];
    }

    // sin + bias + bf16 pack -> ybuf
    #pragma unroll
    for (int v = 0; v < 16; ++v) {
        int o = o0 + v;
        float bo = U[4096 + o];
        unsigned int us[4];
        #pragma unroll
        for (int e = 0; e < 4; ++e) {
            float yv = __sinf(acc[e][v >> 1][v & 1] + bo);
            unsigned int u = __float_as_uint(yv);
            u += 0x7fffu + ((u >> 16) & 1u);   // RNE to bf16
            us[e] = u >> 16;
        }
        uint2 pk;
        pk.x = us[0] | (us[1] << 16);
        pk.y = us[2] | (us[3] << 16);
        *(uint2*)&ybuf[o][s0] = pk;
    }
    __syncthreads();   // ybuf complete; U (W+bias) dead -> reuse for rwT/swT

    // ---- stage rw^T into U[0..4095], sw^T into U[4096..8191] ----
    // (coalesced LDS writes: lanes sweep o at fixed c -> conflict-free)
    #pragma unroll
    for (int r = 0; r < 16; ++r) {
        int idx = r * 256 + tid;
        int o = idx & 63, c = idx >> 6;
        U[c * 64 + o]        = rgv[r];
        U[4096 + c * 64 + o] = sgv[r];
    }
    __syncthreads();

    // ---- phase 2: res/skip = (rw|sw) @ y, packed fp32 ----
    f2 ar[4][8], as_[4][8];
    #pragma unroll
    for (int e = 0; e < 4; ++e)
        #pragma unroll
        for (int p = 0; p < 8; ++p) { f2 z = {0.f, 0.f}; ar[e][p] = z; as_[e][p] = z; }

    #pragma unroll 4
    for (int c = 0; c < 64; ++c) {
        uint2 yu = *(const uint2*)&ybuf[c][s0];
        float y0 = __uint_as_float(yu.x << 16);
        float y1 = __uint_as_float(yu.x & 0xffff0000u);
        float y2 = __uint_as_float(yu.y << 16);
        float y3 = __uint_as_float(yu.y & 0xffff0000u);
        f2 d0 = {y0, y0}, d1 = {y1, y1}, d2 = {y2, y2}, d3 = {y3, y3};
        #pragma unroll
        for (int q = 0; q < 4; ++q) {
            f4 rq = U4[c * 16 + og * 4 + q];
            f4 sq = U4[1024 + c * 16 + og * 4 + q];
            f2 r0 = rq.xy, r1 = rq.zw;
            f2 v0 = sq.xy, v1 = sq.zw;
            ar[0][2*q]  += d0 * r0;  ar[0][2*q+1]  += d0 * r1;
            ar[1][2*q]  += d1 * r0;  ar[1][2*q+1]  += d1 * r1;
            ar[2][2*q]  += d2 * r0;  ar[2][2*q+1]  += d2 * r1;
            ar[3][2*q]  += d3 * r0;  ar[3][2*q+1]  += d3 * r1;
            as_[0][2*q] += d0 * v0;  as_[0][2*q+1] += d0 * v1;
            as_[1][2*q] += d1 * v0;  as_[1][2*q+1] += d1 * v1;
            as_[2][2*q] += d2 * v0;  as_[2][2*q+1] += d2 * v1;
            as_[3][2*q] += d3 * v0;  as_[3][2*q+1] += d3 * v1;
        }
    }

    // ---- epilogue ----
    float* resp = out;
    float* skpp = out + (size_t)B_ * COUT * TT;
    #pragma unroll
    for (int v = 0; v < 16; ++v) {
        int o = o0 + v;
        size_t off = (size_t)(b * COUT + o) * TT + tbase + s0;
        float4 xo = *(const float4*)(x + off);
        float rbv = rb[o], sbv = sb[o];
        float4 ro, so;
        ro.x = (ar[0][v >> 1][v & 1] + rbv + xo.x) * 0.5f;
        ro.y = (ar[1][v >> 1][v & 1] + rbv + xo.y) * 0.5f;
        ro.z = (ar[2][v >> 1][v & 1] + rbv + xo.z) * 0.5f;
        ro.w = (ar[3][v >> 1][v & 1] + rbv + xo.w) * 0.5f;
        so.x = as_[0][v >> 1][v & 1] + sbv;
        so.y = as_[1][v >> 1][v & 1] + sbv;
        so.z = as_[2][v >> 1][v & 1] + sbv;
        so.w = as_[3][v >> 1][v & 1] + sbv;
        *(float4*)(resp + off) = ro;
        *(float4*)(skpp + off) = so;
    }
}

// ---------------------------------------------------------------------------
extern "C" void kernel_launch(void* const* d_in, const int* in_sizes, int n_in,
                              void* d_out, int out_size, void* d_ws, size_t ws_size,
                              hipStream_t stream) {
    const float* x   = (const float*)d_in[0];
    const float* z   = (const float*)d_in[1];
    const float* wm1 = (const float*)d_in[2];
    const float* wb1 = (const float*)d_in[3];
    const float* wm2 = (const float*)d_in[4];
    const float* wb2 = (const float*)d_in[5];
    const float* bm1 = (const float*)d_in[6];
    const float* bb1 = (const float*)d_in[7];
    const float* bm2 = (const float*)d_in[8];
    const float* bb2 = (const float*)d_in[9];
    const float* rw  = (const float*)d_in[10];
    const float* rb  = (const float*)d_in[11];
    const float* sw  = (const float*)d_in[12];
    const float* sb  = (const float*)d_in[13];
    float* out = (float*)d_out;

    float* ws      = (float*)d_ws;
    float* ws_wm2s = ws;             // 131072 floats
    float* ws_h    = ws + 131072;    // 65536 floats
    float* ws_bias = ws + 196608;    // 131072 floats
    float* ws_w    = ws + 327680;    // 8388608 floats

    hipLaunchKernelGGL(k_tapsum, dim3(512), dim3(256), 0, stream, wm2, ws_wm2s);
    hipLaunchKernelGGL(k_hyper_small, dim3(256), dim3(256), 0, stream,
                       z, wm1, wb1, bm1, bb1, bm2, bb2, ws_h, ws_bias);
    hipLaunchKernelGGL(k_weff, dim3(128), dim3(256), 0, stream,
                       ws_wm2s, wb2, ws_h, ws_w);
    hipLaunchKernelGGL(k_main, dim3(2048), dim3(256), 0, stream,
                       x, ws_w, ws_bias, rw, rb, sw, sb, out);
}

// Round 2
// 648.301 us; speedup vs baseline: 1.5842x; 1.5842x over previous
//
#include <hip/hip_runtime.h>
#include <hip/hip_bf16.h>

#define B_    16
#define CIN   64
#define COUT  64
#define ZD    64
#define WHID  32
#define TT    32768
#define KK    128
#define SS    256

// ---------------------------------------------------------------------------
// K0: tap-sum of wm2: wm2s[j][h] = sum_t wm2[(t*4096+j)*32+h], j<4096, h<32
// ---------------------------------------------------------------------------
__global__ void k_tapsum(const float* __restrict__ wm2, float* __restrict__ wm2s) {
    int i = blockIdx.x * 256 + threadIdx.x;
    if (i < 4096 * 32)
        wm2s[i] = wm2[i] + wm2[i + 131072] + wm2[i + 262144];
}

// ---------------------------------------------------------------------------
// K1: per-segment hypernet hidden h (stored) and bias (stored).
// ---------------------------------------------------------------------------
__global__ __launch_bounds__(256) void k_hyper_small(
    const float* __restrict__ z,
    const float* __restrict__ wm1, const float* __restrict__ wb1,
    const float* __restrict__ bm1, const float* __restrict__ bb1,
    const float* __restrict__ bm2, const float* __restrict__ bb2,
    float* __restrict__ ws_h, float* __restrict__ ws_bias)
{
    __shared__ float hb[8][32];
    const int tid = threadIdx.x;
    const int seg = tid >> 5, w = tid & 31;
    const int bk = blockIdx.x * 8 + seg;
    const int b = bk >> 7, k = bk & 127;
    const float* zp = z + b * ZD * KK + k;

    float hv = wb1[w], hbv = bb1[w];
    #pragma unroll
    for (int zz = 0; zz < 64; ++zz) {
        float zv = zp[zz * KK];
        hv  += wm1[w * 64 + zz] * zv;
        hbv += bm1[w * 64 + zz] * zv;
    }
    hv  = fmaxf(hv, 0.f);
    hbv = fmaxf(hbv, 0.f);
    ws_h[bk * 32 + w] = hv;
    hb[seg][w] = hbv;
    __syncthreads();

    #pragma unroll
    for (int t = 0; t < 2; ++t) {
        int o = w + t * 32;
        float acc = bb2[o];
        #pragma unroll
        for (int hh = 0; hh < 32; ++hh)
            acc += bm2[o * 32 + hh] * hb[seg][hh];
        ws_bias[bk * 64 + o] = acc;
    }
}

// ---------------------------------------------------------------------------
// K2: w_eff GEMM: ws_w[bk][j] = wm2s[j][:] @ h[bk][:] + tap-summed wb2[j]
// 512 blocks x 256 threads; one segment per wave (full-GPU grid).
// ---------------------------------------------------------------------------
__global__ __launch_bounds__(256) void k_weff(
    const float* __restrict__ wm2s, const float* __restrict__ wb2,
    const float* __restrict__ ws_h, float* __restrict__ ws_w)
{
    const int tid = threadIdx.x;
    const int wave = tid >> 6, lane = tid & 63;
    const int bk = blockIdx.x * 4 + wave;

    float hreg[32];
    #pragma unroll
    for (int hh = 0; hh < 32; ++hh)
        hreg[hh] = ws_h[bk * 32 + hh];

    for (int jj = 0; jj < 64; ++jj) {
        int j = jj * 64 + lane;
        float4 row[8];
        const float4* rp = (const float4*)(wm2s + j * 32);
        #pragma unroll
        for (int q = 0; q < 8; ++q) row[q] = rp[q];
        float wb = wb2[j] + wb2[j + 4096] + wb2[j + 8192];
        const float* rowf = (const float*)row;
        float acc = wb;
        #pragma unroll
        for (int hh = 0; hh < 32; ++hh)
            acc += rowf[hh] * hreg[hh];
        ws_w[(size_t)bk * 4096 + j] = acc;
    }
}

// ---------------------------------------------------------------------------
// K3: fused main kernel. 1 block per (b,k) segment, 512 threads (8 waves).
// Round-0 proven structure, two changes only:
//   (a) 512 threads/block: per-thread acc footprint halves (64 vs 128 fp32
//       accumulators in phase 2) -> VGPR <=128 under __launch_bounds__(512,4),
//       LDS still 64KB -> 2 blocks/CU -> 16 waves/CU = 4 waves/SIMD (2x the
//       round-0 latency hiding at identical aggregate VALU issue).
//   (b) rw/sw transpose staged via global gather -> 8+8 register prefetch
//       (issued before the sin loop, latency hidden under sin/pack) ->
//       coalesced conflict-free LDS writes (round-0's version was a 64-way
//       bank conflict, 1.6e7 cycles).
// Arithmetic order identical to round 0 (bitwise-same output expected).
// LDS: U = 32KB union (W+bias | rwT+swT) + ybuf 32KB = exactly 64KB.
// ---------------------------------------------------------------------------
__global__ __launch_bounds__(512, 4) void k_main(
    const float* __restrict__ x,
    const float* __restrict__ ws_w, const float* __restrict__ ws_bias,
    const float* __restrict__ rw, const float* __restrict__ rb,
    const float* __restrict__ sw, const float* __restrict__ sb,
    float* __restrict__ out)
{
    __shared__ float U[8192];                               // 32 KB
    __shared__ __align__(16) unsigned short ybuf[64][256];  // 32 KB (bf16)

    const int tid = threadIdx.x;
    const int bk = blockIdx.x;
    const int b = bk >> 7, k = bk & 127;
    const int tbase = k * SS;
    const int sg = tid & 63, og = tid >> 6;      // og in 0..7
    const int s0 = sg * 4, o0 = og * 8;
    float4* U4 = (float4*)U;

    // ---- stage W (4096 floats) into U[0..4095]; bias into U[4096..4159] ----
    {
        const float4* Wg = (const float4*)(ws_w + (size_t)bk * 4096);
        #pragma unroll
        for (int r = 0; r < 2; ++r) U4[tid + 512 * r] = Wg[tid + 512 * r];
        if (tid < 64) U[4096 + tid] = ws_bias[bk * 64 + tid];
    }
    __syncthreads();

    // ---- phase 1: y = sin(x @ W + bias) ----
    float acc[4][8];
    #pragma unroll
    for (int e = 0; e < 4; ++e)
        #pragma unroll
        for (int v = 0; v < 8; ++v) acc[e][v] = 0.f;

    const float* xs = x + (size_t)b * CIN * TT + tbase + s0;
    #pragma unroll 8
    for (int i = 0; i < 64; ++i) {
        float4 xv = *(const float4*)(xs + (size_t)i * TT);
        #pragma unroll
        for (int q = 0; q < 2; ++q) {
            float4 wq = U4[i * 16 + og * 2 + q];
            float wv[4] = {wq.x, wq.y, wq.z, wq.w};
            #pragma unroll
            for (int e2 = 0; e2 < 4; ++e2) {
                acc[0][q * 4 + e2] += xv.x * wv[e2];
                acc[1][q * 4 + e2] += xv.y * wv[e2];
                acc[2][q * 4 + e2] += xv.z * wv[e2];
                acc[3][q * 4 + e2] += xv.w * wv[e2];
            }
        }
    }

    // prefetch rw^T/sw^T gathers (L2-hot 16KB each); latency hides under sin
    float rgv[8], sgv[8];
    #pragma unroll
    for (int r = 0; r < 8; ++r) {
        int idx = r * 512 + tid;           // 0..4095
        int o = idx & 63, c = idx >> 6;    // c = r*8 + og (wave-uniform)
        rgv[r] = rw[o * 64 + c];
        sgv[r] = sw[o * 64 + c];
    }

    // sin + bias + bf16 pack -> ybuf
    #pragma unroll
    for (int v = 0; v < 8; ++v) {
        int o = o0 + v;
        float bo = U[4096 + o];
        unsigned int us[4];
        #pragma unroll
        for (int e = 0; e < 4; ++e) {
            float yv = __sinf(acc[e][v] + bo);
            unsigned int u = __float_as_uint(yv);
            u += 0x7fffu + ((u >> 16) & 1u);   // RNE to bf16
            us[e] = u >> 16;
        }
        uint2 pk;
        pk.x = us[0] | (us[1] << 16);
        pk.y = us[2] | (us[3] << 16);
        *(uint2*)&ybuf[o][s0] = pk;
    }
    __syncthreads();   // ybuf complete; U (W+bias) dead -> reuse for rwT/swT

    // ---- stage rw^T into U[0..4095], sw^T into U[4096..8191] ----
    // lanes sweep o at fixed c -> consecutive LDS addresses, conflict-free
    #pragma unroll
    for (int r = 0; r < 8; ++r) {
        int idx = r * 512 + tid;
        int o = idx & 63, c = idx >> 6;
        U[c * 64 + o]        = rgv[r];
        U[4096 + c * 64 + o] = sgv[r];
    }
    __syncthreads();

    // ---- phase 2: res/skip = (rw|sw) @ y ----
    float ar[4][8], asx[4][8];
    #pragma unroll
    for (int e = 0; e < 4; ++e)
        #pragma unroll
        for (int v = 0; v < 8; ++v) { ar[e][v] = 0.f; asx[e][v] = 0.f; }

    #pragma unroll 4
    for (int c = 0; c < 64; ++c) {
        uint2 yu = *(const uint2*)&ybuf[c][s0];
        float yv[4];
        yv[0] = __uint_as_float(yu.x << 16);
        yv[1] = __uint_as_float(yu.x & 0xffff0000u);
        yv[2] = __uint_as_float(yu.y << 16);
        yv[3] = __uint_as_float(yu.y & 0xffff0000u);
        #pragma unroll
        for (int q = 0; q < 2; ++q) {
            float4 rq = U4[c * 16 + og * 2 + q];
            float4 sq = U4[1024 + c * 16 + og * 2 + q];
            float rv[4] = {rq.x, rq.y, rq.z, rq.w};
            float sv[4] = {sq.x, sq.y, sq.z, sq.w};
            #pragma unroll
            for (int e2 = 0; e2 < 4; ++e2) {
                #pragma unroll
                for (int e = 0; e < 4; ++e) {
                    ar[e][q * 4 + e2]  += yv[e] * rv[e2];
                    asx[e][q * 4 + e2] += yv[e] * sv[e2];
                }
            }
        }
    }

    // ---- epilogue ----
    float* resp = out;
    float* skpp = out + (size_t)B_ * COUT * TT;
    #pragma unroll
    for (int v = 0; v < 8; ++v) {
        int o = o0 + v;
        size_t off = (size_t)(b * COUT + o) * TT + tbase + s0;
        float4 xo = *(const float4*)(x + off);
        float rbv = rb[o], sbv = sb[o];
        float4 ro, so;
        ro.x = (ar[0][v] + rbv + xo.x) * 0.5f;
        ro.y = (ar[1][v] + rbv + xo.y) * 0.5f;
        ro.z = (ar[2][v] + rbv + xo.z) * 0.5f;
        ro.w = (ar[3][v] + rbv + xo.w) * 0.5f;
        so.x = asx[0][v] + sbv;
        so.y = asx[1][v] + sbv;
        so.z = asx[2][v] + sbv;
        so.w = asx[3][v] + sbv;
        *(float4*)(resp + off) = ro;
        *(float4*)(skpp + off) = so;
    }
}

// ---------------------------------------------------------------------------
extern "C" void kernel_launch(void* const* d_in, const int* in_sizes, int n_in,
                              void* d_out, int out_size, void* d_ws, size_t ws_size,
                              hipStream_t stream) {
    const float* x   = (const float*)d_in[0];
    const float* z   = (const float*)d_in[1];
    const float* wm1 = (const float*)d_in[2];
    const float* wb1 = (const float*)d_in[3];
    const float* wm2 = (const float*)d_in[4];
    const float* wb2 = (const float*)d_in[5];
    const float* bm1 = (const float*)d_in[6];
    const float* bb1 = (const float*)d_in[7];
    const float* bm2 = (const float*)d_in[8];
    const float* bb2 = (const float*)d_in[9];
    const float* rw  = (const float*)d_in[10];
    const float* rb  = (const float*)d_in[11];
    const float* sw  = (const float*)d_in[12];
    const float* sb  = (const float*)d_in[13];
    float* out = (float*)d_out;

    float* ws      = (float*)d_ws;
    float* ws_wm2s = ws;             // 131072 floats
    float* ws_h    = ws + 131072;    // 65536 floats
    float* ws_bias = ws + 196608;    // 131072 floats
    float* ws_w    = ws + 327680;    // 8388608 floats

    hipLaunchKernelGGL(k_tapsum, dim3(512), dim3(256), 0, stream, wm2, ws_wm2s);
    hipLaunchKernelGGL(k_hyper_small, dim3(256), dim3(256), 0, stream,
                       z, wm1, wb1, bm1, bb1, bm2, bb2, ws_h, ws_bias);
    hipLaunchKernelGGL(k_weff, dim3(512), dim3(256), 0, stream,
                       ws_wm2s, wb2, ws_h, ws_w);
    hipLaunchKernelGGL(k_main, dim3(2048), dim3(512), 0, stream,
                       x, ws_w, ws_bias, rw, rb, sw, sb, out);
}

// Round 3
// 572.545 us; speedup vs baseline: 1.7938x; 1.1323x over previous
//
#include <hip/hip_runtime.h>
#include <hip/hip_bf16.h>

#define B_    16
#define CIN   64
#define COUT  64
#define ZD    64
#define WHID  32
#define TT    32768
#define KK    128
#define SS    256

// ---------------------------------------------------------------------------
// K0: tap-sums.
//   wm2s[j][h] = sum_t wm2[(t*4096+j)*32+h], j<4096, h<32
//   wbs[j]     = wb2[j] + wb2[j+4096] + wb2[j+8192]
// ---------------------------------------------------------------------------
__global__ void k_tapsum(const float* __restrict__ wm2, const float* __restrict__ wb2,
                         float* __restrict__ wm2s, float* __restrict__ wbs) {
    int i = blockIdx.x * 256 + threadIdx.x;
    if (i < 4096 * 32)
        wm2s[i] = wm2[i] + wm2[i + 131072] + wm2[i + 262144];
    if (i < 4096)
        wbs[i] = wb2[i] + wb2[i + 4096] + wb2[i + 8192];
}

// ---------------------------------------------------------------------------
// K1: per-segment hypernet hidden h (stored) and bias (stored).
// ---------------------------------------------------------------------------
__global__ __launch_bounds__(256) void k_hyper_small(
    const float* __restrict__ z,
    const float* __restrict__ wm1, const float* __restrict__ wb1,
    const float* __restrict__ bm1, const float* __restrict__ bb1,
    const float* __restrict__ bm2, const float* __restrict__ bb2,
    float* __restrict__ ws_h, float* __restrict__ ws_bias)
{
    __shared__ float hb[8][32];
    const int tid = threadIdx.x;
    const int seg = tid >> 5, w = tid & 31;
    const int bk = blockIdx.x * 8 + seg;
    const int b = bk >> 7, k = bk & 127;
    const float* zp = z + b * ZD * KK + k;

    float hv = wb1[w], hbv = bb1[w];
    #pragma unroll
    for (int zz = 0; zz < 64; ++zz) {
        float zv = zp[zz * KK];
        hv  += wm1[w * 64 + zz] * zv;
        hbv += bm1[w * 64 + zz] * zv;
    }
    hv  = fmaxf(hv, 0.f);
    hbv = fmaxf(hbv, 0.f);
    ws_h[bk * 32 + w] = hv;
    hb[seg][w] = hbv;
    __syncthreads();

    #pragma unroll
    for (int t = 0; t < 2; ++t) {
        int o = w + t * 32;
        float acc = bb2[o];
        #pragma unroll
        for (int hh = 0; hh < 32; ++hh)
            acc += bm2[o * 32 + hh] * hb[seg][hh];
        ws_bias[bk * 64 + o] = acc;
    }
}

// ---------------------------------------------------------------------------
// K2 (fused main). 1 block per (b,k) segment, 512 threads (8 waves).
// Prologue: W[j] = wm2s[j][:] @ h + wbs[j]  computed in-block -> U[0..4095]
//   (bitwise-identical order to the old k_weff; wm2s is 512KB L2/L3-hot;
//    thread owns full rows j=r*512+tid, q-reads of a row share 64B lines
//    so the 128B-stride pattern is L1-friendly; kills the 67MB ws_w
//    HBM round-trip and the k_weff launch).
// Phase 1: y = sin(x@W + bias) with register-double-buffered x (4-row
//   batches, next batch's loads issued before current batch's FMAs; batch 0
//   issued at kernel start so it hides under the W prologue).
// Phase 2: res/skip = (rw|sw)@y from bf16 ybuf (unchanged from round 2).
// LDS: U = 32KB union (W+bias | rwT+swT) + ybuf 32KB = exactly 64KB.
// ---------------------------------------------------------------------------
__global__ __launch_bounds__(512, 4) void k_main(
    const float* __restrict__ x,
    const float* __restrict__ wm2s, const float* __restrict__ wbs,
    const float* __restrict__ ws_h, const float* __restrict__ ws_bias,
    const float* __restrict__ rw, const float* __restrict__ rb,
    const float* __restrict__ sw, const float* __restrict__ sb,
    float* __restrict__ out)
{
    __shared__ float U[8192];                               // 32 KB
    __shared__ __align__(16) unsigned short ybuf[64][256];  // 32 KB (bf16)

    const int tid = threadIdx.x;
    const int bk = blockIdx.x;
    const int b = bk >> 7, k = bk & 127;
    const int tbase = k * SS;
    const int sg = tid & 63, og = tid >> 6;      // og in 0..7
    const int s0 = sg * 4, o0 = og * 8;
    float4* U4 = (float4*)U;

    // ---- issue x batch 0 immediately (hides under W prologue) ----
    const float* xs = x + (size_t)b * CIN * TT + tbase + s0;
    float4 xbA[4], xbB[4];
    #pragma unroll
    for (int r = 0; r < 4; ++r)
        xbA[r] = *(const float4*)(xs + (size_t)r * TT);

    // ---- W prologue: U[j] = wm2s[j][:] @ h + wbs[j]  (8 rows/thread) ----
    {
        float hreg[32];                    // bk-uniform -> scalar loads
        #pragma unroll
        for (int hh = 0; hh < 32; ++hh) hreg[hh] = ws_h[bk * 32 + hh];
        if (tid < 64) U[4096 + tid] = ws_bias[bk * 64 + tid];

        #pragma unroll
        for (int r = 0; r < 8; ++r) {
            const int j = r * 512 + tid;
            const float4* rp = (const float4*)(wm2s + j * 32);
            float4 row[8];
            #pragma unroll
            for (int q = 0; q < 8; ++q) row[q] = rp[q];
            const float* rowf = (const float*)row;
            float a = wbs[j];
            #pragma unroll
            for (int hh = 0; hh < 32; ++hh)
                a += rowf[hh] * hreg[hh];
            U[j] = a;
        }
    }
    __syncthreads();

    // ---- phase 1: y = sin(x @ W + bias), double-buffered x batches ----
    float acc[4][8];
    #pragma unroll
    for (int e = 0; e < 4; ++e)
        #pragma unroll
        for (int v = 0; v < 8; ++v) acc[e][v] = 0.f;

    #pragma unroll
    for (int jb = 0; jb < 16; ++jb) {
        // issue next batch (static buffer choice: jb is compile-time const)
        if (jb < 15) {
            #pragma unroll
            for (int r = 0; r < 4; ++r) {
                float4 v = *(const float4*)(xs + (size_t)((jb + 1) * 4 + r) * TT);
                if ((jb & 1) == 0) xbB[r] = v; else xbA[r] = v;
            }
        }
        // consume current batch
        #pragma unroll
        for (int r = 0; r < 4; ++r) {
            float4 xv = ((jb & 1) == 0) ? xbA[r] : xbB[r];
            const int c = jb * 4 + r;
            #pragma unroll
            for (int q = 0; q < 2; ++q) {
                float4 wq = U4[c * 16 + og * 2 + q];
                float wv[4] = {wq.x, wq.y, wq.z, wq.w};
                #pragma unroll
                for (int e2 = 0; e2 < 4; ++e2) {
                    acc[0][q * 4 + e2] += xv.x * wv[e2];
                    acc[1][q * 4 + e2] += xv.y * wv[e2];
                    acc[2][q * 4 + e2] += xv.z * wv[e2];
                    acc[3][q * 4 + e2] += xv.w * wv[e2];
                }
            }
        }
    }

    // prefetch rw^T/sw^T gathers (L2-hot 16KB each); latency hides under sin
    float rgv[8], sgv[8];
    #pragma unroll
    for (int r = 0; r < 8; ++r) {
        int idx = r * 512 + tid;           // 0..4095
        int o = idx & 63, c = idx >> 6;
        rgv[r] = rw[o * 64 + c];
        sgv[r] = sw[o * 64 + c];
    }

    // sin + bias + bf16 pack -> ybuf
    #pragma unroll
    for (int v = 0; v < 8; ++v) {
        int o = o0 + v;
        float bo = U[4096 + o];
        unsigned int us[4];
        #pragma unroll
        for (int e = 0; e < 4; ++e) {
            float yv = __sinf(acc[e][v] + bo);
            unsigned int u = __float_as_uint(yv);
            u += 0x7fffu + ((u >> 16) & 1u);   // RNE to bf16
            us[e] = u >> 16;
        }
        uint2 pk;
        pk.x = us[0] | (us[1] << 16);
        pk.y = us[2] | (us[3] << 16);
        *(uint2*)&ybuf[o][s0] = pk;
    }
    __syncthreads();   // ybuf complete; U (W+bias) dead -> reuse for rwT/swT

    // ---- stage rw^T into U[0..4095], sw^T into U[4096..8191] ----
    #pragma unroll
    for (int r = 0; r < 8; ++r) {
        int idx = r * 512 + tid;
        int o = idx & 63, c = idx >> 6;
        U[c * 64 + o]        = rgv[r];
        U[4096 + c * 64 + o] = sgv[r];
    }
    __syncthreads();

    // ---- phase 2: res/skip = (rw|sw) @ y ----
    float ar[4][8], asx[4][8];
    #pragma unroll
    for (int e = 0; e < 4; ++e)
        #pragma unroll
        for (int v = 0; v < 8; ++v) { ar[e][v] = 0.f; asx[e][v] = 0.f; }

    #pragma unroll 4
    for (int c = 0; c < 64; ++c) {
        uint2 yu = *(const uint2*)&ybuf[c][s0];
        float yv[4];
        yv[0] = __uint_as_float(yu.x << 16);
        yv[1] = __uint_as_float(yu.x & 0xffff0000u);
        yv[2] = __uint_as_float(yu.y << 16);
        yv[3] = __uint_as_float(yu.y & 0xffff0000u);
        #pragma unroll
        for (int q = 0; q < 2; ++q) {
            float4 rq = U4[c * 16 + og * 2 + q];
            float4 sq = U4[1024 + c * 16 + og * 2 + q];
            float rv[4] = {rq.x, rq.y, rq.z, rq.w};
            float sv[4] = {sq.x, sq.y, sq.z, sq.w};
            #pragma unroll
            for (int e2 = 0; e2 < 4; ++e2) {
                #pragma unroll
                for (int e = 0; e < 4; ++e) {
                    ar[e][q * 4 + e2]  += yv[e] * rv[e2];
                    asx[e][q * 4 + e2] += yv[e] * sv[e2];
                }
            }
        }
    }

    // ---- epilogue ----
    float* resp = out;
    float* skpp = out + (size_t)B_ * COUT * TT;
    #pragma unroll
    for (int v = 0; v < 8; ++v) {
        int o = o0 + v;
        size_t off = (size_t)(b * COUT + o) * TT + tbase + s0;
        float4 xo = *(const float4*)(x + off);
        float rbv = rb[o], sbv = sb[o];
        float4 ro, so;
        ro.x = (ar[0][v] + rbv + xo.x) * 0.5f;
        ro.y = (ar[1][v] + rbv + xo.y) * 0.5f;
        ro.z = (ar[2][v] + rbv + xo.z) * 0.5f;
        ro.w = (ar[3][v] + rbv + xo.w) * 0.5f;
        so.x = asx[0][v] + sbv;
        so.y = asx[1][v] + sbv;
        so.z = asx[2][v] + sbv;
        so.w = asx[3][v] + sbv;
        *(float4*)(resp + off) = ro;
        *(float4*)(skpp + off) = so;
    }
}

// ---------------------------------------------------------------------------
extern "C" void kernel_launch(void* const* d_in, const int* in_sizes, int n_in,
                              void* d_out, int out_size, void* d_ws, size_t ws_size,
                              hipStream_t stream) {
    const float* x   = (const float*)d_in[0];
    const float* z   = (const float*)d_in[1];
    const float* wm1 = (const float*)d_in[2];
    const float* wb1 = (const float*)d_in[3];
    const float* wm2 = (const float*)d_in[4];
    const float* wb2 = (const float*)d_in[5];
    const float* bm1 = (const float*)d_in[6];
    const float* bb1 = (const float*)d_in[7];
    const float* bm2 = (const float*)d_in[8];
    const float* bb2 = (const float*)d_in[9];
    const float* rw  = (const float*)d_in[10];
    const float* rb  = (const float*)d_in[11];
    const float* sw  = (const float*)d_in[12];
    const float* sb  = (const float*)d_in[13];
    float* out = (float*)d_out;

    float* ws      = (float*)d_ws;
    float* ws_wm2s = ws;             // 131072 floats
    float* ws_wbs  = ws + 131072;    // 4096 floats
    float* ws_h    = ws + 135168;    // 65536 floats
    float* ws_bias = ws + 200704;    // 131072 floats

    hipLaunchKernelGGL(k_tapsum, dim3(512), dim3(256), 0, stream, wm2, wb2, ws_wm2s, ws_wbs);
    hipLaunchKernelGGL(k_hyper_small, dim3(256), dim3(256), 0, stream,
                       z, wm1, wb1, bm1, bb1, bm2, bb2, ws_h, ws_bias);
    hipLaunchKernelGGL(k_main, dim3(2048), dim3(512), 0, stream,
                       x, ws_wm2s, ws_wbs, ws_h, ws_bias, rw, rb, sw, sb, out);
}

// Round 4
// 524.030 us; speedup vs baseline: 1.9598x; 1.0926x over previous
//
#include <hip/hip_runtime.h>
#include <hip/hip_bf16.h>

#define B_    16
#define CIN   64
#define COUT  64
#define ZD    64
#define WHID  32
#define TT    32768
#define KK    128
#define SS    256

typedef float f2 __attribute__((ext_vector_type(2)));

// ---------------------------------------------------------------------------
// K0: tap-sums.
//   wm2s[j][h] = sum_t wm2[(t*4096+j)*32+h], j<4096, h<32
//   wbs[j]     = wb2[j] + wb2[j+4096] + wb2[j+8192]
// ---------------------------------------------------------------------------
__global__ void k_tapsum(const float* __restrict__ wm2, const float* __restrict__ wb2,
                         float* __restrict__ wm2s, float* __restrict__ wbs) {
    int i = blockIdx.x * 256 + threadIdx.x;
    if (i < 4096 * 32)
        wm2s[i] = wm2[i] + wm2[i + 131072] + wm2[i + 262144];
    if (i < 4096)
        wbs[i] = wb2[i] + wb2[i + 4096] + wb2[i + 8192];
}

// ---------------------------------------------------------------------------
// K1: per-segment hypernet hidden h (stored) and bias (stored).
// ---------------------------------------------------------------------------
__global__ __launch_bounds__(256) void k_hyper_small(
    const float* __restrict__ z,
    const float* __restrict__ wm1, const float* __restrict__ wb1,
    const float* __restrict__ bm1, const float* __restrict__ bb1,
    const float* __restrict__ bm2, const float* __restrict__ bb2,
    float* __restrict__ ws_h, float* __restrict__ ws_bias)
{
    __shared__ float hb[8][32];
    const int tid = threadIdx.x;
    const int seg = tid >> 5, w = tid & 31;
    const int bk = blockIdx.x * 8 + seg;
    const int b = bk >> 7, k = bk & 127;
    const float* zp = z + b * ZD * KK + k;

    float hv = wb1[w], hbv = bb1[w];
    #pragma unroll
    for (int zz = 0; zz < 64; ++zz) {
        float zv = zp[zz * KK];
        hv  += wm1[w * 64 + zz] * zv;
        hbv += bm1[w * 64 + zz] * zv;
    }
    hv  = fmaxf(hv, 0.f);
    hbv = fmaxf(hbv, 0.f);
    ws_h[bk * 32 + w] = hv;
    hb[seg][w] = hbv;
    __syncthreads();

    #pragma unroll
    for (int t = 0; t < 2; ++t) {
        int o = w + t * 32;
        float acc = bb2[o];
        #pragma unroll
        for (int hh = 0; hh < 32; ++hh)
            acc += bm2[o * 32 + hh] * hb[seg][hh];
        ws_bias[bk * 64 + o] = acc;
    }
}

// ---------------------------------------------------------------------------
// K2: w_eff GEMM, tiled row-stationary.
// 512 blocks x 256 threads. Block = (j-tile of 256) x (bk-tile of 64).
// Thread owns one wm2s row (32 floats, registers); h-tile (64 segs x 32) in
// 8KB LDS, read as wave-uniform broadcasts. Outputs coalesced (256
// consecutive j per store sweep). Same FMA order as before -> bitwise-same W.
// ---------------------------------------------------------------------------
__global__ __launch_bounds__(256, 2) void k_weff(
    const float* __restrict__ wm2s, const float* __restrict__ wbs,
    const float* __restrict__ ws_h, float* __restrict__ ws_w)
{
    __shared__ float hsh[64 * 32];   // 8 KB
    const int tid = threadIdx.x;
    const int jt = blockIdx.x & 15, bt = blockIdx.x >> 4;
    const int j = jt * 256 + tid;
    const int bk0 = bt * 64;

    // stage h tile (2048 floats, coalesced)
    #pragma unroll
    for (int r = 0; r < 8; ++r)
        hsh[r * 256 + tid] = ws_h[bk0 * 32 + r * 256 + tid];

    // own row in registers
    float4 row[8];
    const float4* rp = (const float4*)(wm2s + j * 32);
    #pragma unroll
    for (int q = 0; q < 8; ++q) row[q] = rp[q];
    const float* rowf = (const float*)row;
    const float wb = wbs[j];
    __syncthreads();

    #pragma unroll 4
    for (int bk = 0; bk < 64; ++bk) {
        float acc = wb;
        #pragma unroll
        for (int hh = 0; hh < 32; ++hh)
            acc += rowf[hh] * hsh[bk * 32 + hh];
        ws_w[(size_t)(bk0 + bk) * 4096 + j] = acc;
    }
}

// ---------------------------------------------------------------------------
// K3: fused main kernel. 1 block per (b,k) segment, 512 threads (8 waves).
// Memory structure identical to round 2 (proven: 0 bank conflicts, 41% occ).
// ONE change: phase-1/phase-2 inner products paired along the output (e2)
// axis into float2 ext-vectors -> v_pk_fma_f32 (2 fp32 FMA / inst), halving
// the VALU-issue floor. Pair (v,v+1) of the old scalar acc maps to the two
// lanes of acc2[.][v>>1]; each scalar slot sees the identical FMA sequence
// -> bitwise-identical results.
// LDS: U = 32KB union (W+bias | rwT+swT) + ybuf 32KB = exactly 64KB.
// ---------------------------------------------------------------------------
__global__ __launch_bounds__(512, 4) void k_main(
    const float* __restrict__ x,
    const float* __restrict__ ws_w, const float* __restrict__ ws_bias,
    const float* __restrict__ rw, const float* __restrict__ rb,
    const float* __restrict__ sw, const float* __restrict__ sb,
    float* __restrict__ out)
{
    __shared__ float U[8192];                               // 32 KB
    __shared__ __align__(16) unsigned short ybuf[64][256];  // 32 KB (bf16)

    const int tid = threadIdx.x;
    const int bk = blockIdx.x;
    const int b = bk >> 7, k = bk & 127;
    const int tbase = k * SS;
    const int sg = tid & 63, og = tid >> 6;      // og in 0..7 (wave-uniform)
    const int s0 = sg * 4, o0 = og * 8;
    float4* U4 = (float4*)U;

    // ---- stage W (4096 floats) into U[0..4095]; bias into U[4096..4159] ----
    {
        const float4* Wg = (const float4*)(ws_w + (size_t)bk * 4096);
        #pragma unroll
        for (int r = 0; r < 2; ++r) U4[tid + 512 * r] = Wg[tid + 512 * r];
        if (tid < 64) U[4096 + tid] = ws_bias[bk * 64 + tid];
    }
    __syncthreads();

    // ---- phase 1: y = sin(x @ W + bias), packed fp32 ----
    f2 acc2[4][4];
    #pragma unroll
    for (int e = 0; e < 4; ++e)
        #pragma unroll
        for (int p = 0; p < 4; ++p) { f2 zz = {0.f, 0.f}; acc2[e][p] = zz; }

    const float* xs = x + (size_t)b * CIN * TT + tbase + s0;
    #pragma unroll 8
    for (int i = 0; i < 64; ++i) {
        float4 xv = *(const float4*)(xs + (size_t)i * TT);
        f2 xs0 = {xv.x, xv.x}, xs1 = {xv.y, xv.y};
        f2 xs2 = {xv.z, xv.z}, xs3 = {xv.w, xv.w};
        #pragma unroll
        for (int q = 0; q < 2; ++q) {
            float4 wq = U4[i * 16 + og * 2 + q];
            f2 w0 = {wq.x, wq.y}, w1 = {wq.z, wq.w};
            acc2[0][q * 2]     += xs0 * w0;
            acc2[0][q * 2 + 1] += xs0 * w1;
            acc2[1][q * 2]     += xs1 * w0;
            acc2[1][q * 2 + 1] += xs1 * w1;
            acc2[2][q * 2]     += xs2 * w0;
            acc2[2][q * 2 + 1] += xs2 * w1;
            acc2[3][q * 2]     += xs3 * w0;
            acc2[3][q * 2 + 1] += xs3 * w1;
        }
    }

    // prefetch rw^T/sw^T gathers (L2-hot 16KB each); latency hides under sin
    float rgv[8], sgv[8];
    #pragma unroll
    for (int r = 0; r < 8; ++r) {
        int idx = r * 512 + tid;           // 0..4095
        int o = idx & 63, c = idx >> 6;
        rgv[r] = rw[o * 64 + c];
        sgv[r] = sw[o * 64 + c];
    }

    // sin + bias + bf16 pack -> ybuf
    #pragma unroll
    for (int v = 0; v < 8; ++v) {
        int o = o0 + v;
        float bo = U[4096 + o];
        unsigned int us[4];
        #pragma unroll
        for (int e = 0; e < 4; ++e) {
            float yv = __sinf(acc2[e][v >> 1][v & 1] + bo);
            unsigned int u = __float_as_uint(yv);
            u += 0x7fffu + ((u >> 16) & 1u);   // RNE to bf16
            us[e] = u >> 16;
        }
        uint2 pk;
        pk.x = us[0] | (us[1] << 16);
        pk.y = us[2] | (us[3] << 16);
        *(uint2*)&ybuf[o][s0] = pk;
    }
    __syncthreads();   // ybuf complete; U (W+bias) dead -> reuse for rwT/swT

    // ---- stage rw^T into U[0..4095], sw^T into U[4096..8191] ----
    #pragma unroll
    for (int r = 0; r < 8; ++r) {
        int idx = r * 512 + tid;
        int o = idx & 63, c = idx >> 6;
        U[c * 64 + o]        = rgv[r];
        U[4096 + c * 64 + o] = sgv[r];
    }
    __syncthreads();

    // ---- phase 2: res/skip = (rw|sw) @ y, packed fp32 ----
    f2 ar2[4][4], as2[4][4];
    #pragma unroll
    for (int e = 0; e < 4; ++e)
        #pragma unroll
        for (int p = 0; p < 4; ++p) { f2 zz = {0.f, 0.f}; ar2[e][p] = zz; as2[e][p] = zz; }

    #pragma unroll 4
    for (int c = 0; c < 64; ++c) {
        uint2 yu = *(const uint2*)&ybuf[c][s0];
        float y0 = __uint_as_float(yu.x << 16);
        float y1 = __uint_as_float(yu.x & 0xffff0000u);
        float y2 = __uint_as_float(yu.y << 16);
        float y3 = __uint_as_float(yu.y & 0xffff0000u);
        f2 d0 = {y0, y0}, d1 = {y1, y1}, d2 = {y2, y2}, d3 = {y3, y3};
        #pragma unroll
        for (int q = 0; q < 2; ++q) {
            float4 rq = U4[c * 16 + og * 2 + q];
            float4 sq = U4[1024 + c * 16 + og * 2 + q];
            f2 r0 = {rq.x, rq.y}, r1 = {rq.z, rq.w};
            f2 v0 = {sq.x, sq.y}, v1 = {sq.z, sq.w};
            ar2[0][q * 2]     += d0 * r0;
            ar2[0][q * 2 + 1] += d0 * r1;
            ar2[1][q * 2]     += d1 * r0;
            ar2[1][q * 2 + 1] += d1 * r1;
            ar2[2][q * 2]     += d2 * r0;
            ar2[2][q * 2 + 1] += d2 * r1;
            ar2[3][q * 2]     += d3 * r0;
            ar2[3][q * 2 + 1] += d3 * r1;
            as2[0][q * 2]     += d0 * v0;
            as2[0][q * 2 + 1] += d0 * v1;
            as2[1][q * 2]     += d1 * v0;
            as2[1][q * 2 + 1] += d1 * v1;
            as2[2][q * 2]     += d2 * v0;
            as2[2][q * 2 + 1] += d2 * v1;
            as2[3][q * 2]     += d3 * v0;
            as2[3][q * 2 + 1] += d3 * v1;
        }
    }

    // ---- epilogue ----
    float* resp = out;
    float* skpp = out + (size_t)B_ * COUT * TT;
    #pragma unroll
    for (int v = 0; v < 8; ++v) {
        int o = o0 + v;
        size_t off = (size_t)(b * COUT + o) * TT + tbase + s0;
        float4 xo = *(const float4*)(x + off);
        float rbv = rb[o], sbv = sb[o];
        float4 ro, so;
        ro.x = (ar2[0][v >> 1][v & 1] + rbv + xo.x) * 0.5f;
        ro.y = (ar2[1][v >> 1][v & 1] + rbv + xo.y) * 0.5f;
        ro.z = (ar2[2][v >> 1][v & 1] + rbv + xo.z) * 0.5f;
        ro.w = (ar2[3][v >> 1][v & 1] + rbv + xo.w) * 0.5f;
        so.x = as2[0][v >> 1][v & 1] + sbv;
        so.y = as2[1][v >> 1][v & 1] + sbv;
        so.z = as2[2][v >> 1][v & 1] + sbv;
        so.w = as2[3][v >> 1][v & 1] + sbv;
        *(float4*)(resp + off) = ro;
        *(float4*)(skpp + off) = so;
    }
}

// ---------------------------------------------------------------------------
extern "C" void kernel_launch(void* const* d_in, const int* in_sizes, int n_in,
                              void* d_out, int out_size, void* d_ws, size_t ws_size,
                              hipStream_t stream) {
    const float* x   = (const float*)d_in[0];
    const float* z   = (const float*)d_in[1];
    const float* wm1 = (const float*)d_in[2];
    const float* wb1 = (const float*)d_in[3];
    const float* wm2 = (const float*)d_in[4];
    const float* wb2 = (const float*)d_in[5];
    const float* bm1 = (const float*)d_in[6];
    const float* bb1 = (const float*)d_in[7];
    const float* bm2 = (const float*)d_in[8];
    const float* bb2 = (const float*)d_in[9];
    const float* rw  = (const float*)d_in[10];
    const float* rb  = (const float*)d_in[11];
    const float* sw  = (const float*)d_in[12];
    const float* sb  = (const float*)d_in[13];
    float* out = (float*)d_out;

    float* ws      = (float*)d_ws;
    float* ws_wm2s = ws;             // 131072 floats
    float* ws_wbs  = ws + 131072;    // 4096 floats
    float* ws_h    = ws + 135168;    // 65536 floats
    float* ws_bias = ws + 200704;    // 131072 floats
    float* ws_w    = ws + 331776;    // 8388608 floats

    hipLaunchKernelGGL(k_tapsum, dim3(512), dim3(256), 0, stream, wm2, wb2, ws_wm2s, ws_wbs);
    hipLaunchKernelGGL(k_hyper_small, dim3(256), dim3(256), 0, stream,
                       z, wm1, wb1, bm1, bb1, bm2, bb2, ws_h, ws_bias);
    hipLaunchKernelGGL(k_weff, dim3(512), dim3(256), 0, stream,
                       ws_wm2s, ws_wbs, ws_h, ws_w);
    hipLaunchKernelGGL(k_main, dim3(2048), dim3(512), 0, stream,
                       x, ws_w, ws_bias, rw, rb, sw, sb, out);
}